// Round 6
// baseline (250.707 us; speedup 1.0000x reference)
//
#include <hip/hip_runtime.h>
#include <math.h>

// EnergySRB, R6: MLP fix. R2/R5 proved the compiler will not keep >~6 VGPR
// loads in flight (VGPR_Count pinned at 52); achieved BW 1.36 TB/s matches
// Little's law at ~2KB in flight/CU. Fix: stage ai0/ai1/dist tiles into LDS
// with fire-and-forget __builtin_amdgcn_global_load_lds (width 16) -- 48KB
// in flight per CU per stage burst -- then consume from LDS. m97-proven
// single-buffer issue->barrier->consume shape.
// LDS: 64KB species + 16KB bins + 48KB stage + tab = 128.2KB, 1 block/CU.

#define NT        1024
#define NBLK      256
#define CSTAGE    4096                      // pairs per stage
#define SCALE_F   134217728.0f              // 2^27
#define INV_SCALE 7.450580596923828125e-9   // 2^-27, exact in double

typedef const __attribute__((address_space(1))) unsigned gas_u32;
typedef __attribute__((address_space(3))) unsigned       las_u32;

__device__ __forceinline__ void stage16(const void* g, void* l) {
    // per-lane gptr (base + lane*16); wave-uniform LDS base, HW scatters
    // lane i -> ldsbase + i*16.
    __builtin_amdgcn_global_load_lds((gas_u32*)g, (las_u32*)l, 16, 0, 0);
}

// ---------------------------------------------------------------------------
// pack species (values 0..3) into 2-bit words. 262144 atoms -> 64KB.
__global__ void pack_species_kernel(const int* __restrict__ sp,
                                    unsigned* __restrict__ packed, int nwords) {
    int w = blockIdx.x * blockDim.x + threadIdx.x;
    if (w >= nwords) return;
    const int4* p4 = (const int4*)(sp + (w << 4));
    int4 a = p4[0], b = p4[1], c = p4[2], d = p4[3];
    unsigned v =
        (unsigned)(a.x & 3)        | ((unsigned)(a.y & 3) << 2)  |
        ((unsigned)(a.z & 3) << 4) | ((unsigned)(a.w & 3) << 6)  |
        ((unsigned)(b.x & 3) << 8) | ((unsigned)(b.y & 3) << 10) |
        ((unsigned)(b.z & 3) << 12)| ((unsigned)(b.w & 3) << 14) |
        ((unsigned)(c.x & 3) << 16)| ((unsigned)(c.y & 3) << 18) |
        ((unsigned)(c.z & 3) << 20)| ((unsigned)(c.w & 3) << 22) |
        ((unsigned)(d.x & 3) << 24)| ((unsigned)(d.y & 3) << 26) |
        ((unsigned)(d.z & 3) << 28)| ((unsigned)(d.w & 3) << 30);
    packed[w] = v;
}

// ---------------------------------------------------------------------------
// init: species passthrough to out[0:n_species); zero the u64 accumulator.
__global__ void init_kernel(const int* __restrict__ species,
                            float* __restrict__ out,
                            unsigned long long* __restrict__ acc,
                            int n_species, int n_mol) {
    int i = blockIdx.x * blockDim.x + threadIdx.x;
    if (i < n_species) out[i] = (float)species[i];
    if (i < n_mol)     acc[i] = 0ull;
}

// ---------------------------------------------------------------------------
// Main kernel: async-staged pair stream.
__global__ __launch_bounds__(NT, 4)
void srb_async(const unsigned* __restrict__ packed_ws,
               const int* __restrict__ ai,     // [2, P]
               const float* __restrict__ dist, // [P] angstrom
               const float* __restrict__ pre_tab,   // 16 floats (negative)
               const float* __restrict__ dfac_tab,  // 16 floats
               unsigned long long* __restrict__ acc, // [n_mol]
               int P, int mol_shift) {
    __shared__ unsigned packed[16384];   // 64KB species (2-bit)
    __shared__ unsigned binsu[4096];     // 16KB fixed-point mol sums
    __shared__ unsigned sa0[CSTAGE];     // 16KB staged atom0
    __shared__ unsigned sa1[CSTAGE];     // 16KB staged atom1
    __shared__ float    sd [CSTAGE];     // 16KB staged distances
    __shared__ float2   tabr[4][18];     // 4 padded copies (|pre|, dfac)

    const int t = threadIdx.x;
    for (int i = t; i < 4096; i += NT) binsu[i] = 0u;
    if (t < 64) {
        int e = t & 15;
        tabr[t >> 4][e] = make_float2(-pre_tab[e], dfac_tab[e]);
    }
    {
        int4* dst = (int4*)packed;
        const int4* src = (const int4*)packed_ws;
        for (int i = t; i < 4096; i += NT) dst[i] = src[i];
    }

    const float a2b   = (float)1.8897261258369282;
    const float rc    = (float)(5.2 * 1.8897261258369282);
    const float rcinv = (float)(1.0 / (5.2 * 1.8897261258369282));
    const int   copy  = t & 3;
    const int   wave  = t >> 6;
    const int   lane  = t & 63;

    const unsigned* ai0 = (const unsigned*)ai;
    const unsigned* ai1 = (const unsigned*)(ai + P);

    const int ppb  = P / (int)gridDim.x;          // pairs per block (65536)
    const int base = (int)blockIdx.x * ppb;

    // wave w stages dwords [w*256, w*256+256) of each buffer (1KB/instr)
    const int woff = wave << 8;
    unsigned* lds0 = &sa0[woff];
    unsigned* lds1 = &sa1[woff];
    float*    ldsd = &sd[woff];

    __syncthreads();  // packed/binsu/tab ready

    for (int s = 0; s < ppb; s += CSTAGE) {
        const int goff = base + s + woff + (lane << 2); // dword idx, lane*16B
        stage16(ai0  + goff, lds0);
        stage16(ai1  + goff, lds1);
        stage16(dist + goff, ldsd);
        __syncthreads();  // vmcnt drain: staged tile visible to all

        // thread t consumes stage-local pairs 4t..4t+3 (b128 stride-1 reads)
        uint4  A0 = ((const uint4*)sa0)[t];
        uint4  A1 = ((const uint4*)sa1)[t];
        float4 DD = ((const float4*)sd)[t];

        unsigned a0[4] = { A0.x, A0.y, A0.z, A0.w };
        unsigned a1[4] = { A1.x, A1.y, A1.z, A1.w };
        float    dd[4] = { DD.x, DD.y, DD.z, DD.w };

        unsigned w0[4], w1[4];
        #pragma unroll
        for (int k = 0; k < 4; ++k) w0[k] = packed[a0[k] >> 4];
        #pragma unroll
        for (int k = 0; k < 4; ++k) w1[k] = packed[a1[k] >> 4];

        float2 td[4];
        #pragma unroll
        for (int k = 0; k < 4; ++k) {
            unsigned s0 = (w0[k] >> ((a0[k] & 15u) << 1)) & 3u;
            unsigned s1 = (w1[k] >> ((a1[k] & 15u) << 1)) & 3u;
            td[k] = tabr[copy][(s0 << 2) | s1];
        }

        #pragma unroll
        for (int k = 0; k < 4; ++k) {
            float db  = dd[k] * a2b;
            float x   = db * rcinv;
            float arg = td[k].y * db + (1.0f - 1.0f / (1.0f - x * x));
            float mag = td[k].x * __expf(arg);   // td.x = |pre| > 0
            mag = (db < rc) ? mag : 0.0f;        // exact 0 beyond cutoff
            unsigned q = (unsigned)(mag * SCALE_F); // trunc, < 2^21
            atomicAdd(&binsu[a0[k] >> mol_shift], q); // native ds_add_u32
        }
        __syncthreads();  // consumed before next stage overwrites
    }

    for (int i = t; i < 4096; i += NT) {
        unsigned v = binsu[i];
        if (v) atomicAdd(&acc[i], (unsigned long long)v); // native u64 atomic
    }
}

// ---------------------------------------------------------------------------
// final: out_e[m] = energies[m] - acc[m] * 2^-27  (exact in double)
__global__ void final_kernel(const unsigned long long* __restrict__ acc,
                             const float* __restrict__ energies,
                             float* __restrict__ out_e, int n_mol) {
    int m = blockIdx.x * blockDim.x + threadIdx.x;
    if (m < n_mol)
        out_e[m] = energies[m] - (float)((double)acc[m] * INV_SCALE);
}

// ---------------------------------------------------------------------------
// Fallback main kernel (sizes not multiple of NBLK*CSTAGE): R4 structure,
// known-good at ~80us.
__global__ __launch_bounds__(NT, 1)
void srb_fused_u32(const unsigned* __restrict__ packed_ws,
                   const int* __restrict__ ai,
                   const float* __restrict__ dist,
                   const float* __restrict__ pre_tab,
                   const float* __restrict__ dfac_tab,
                   unsigned long long* __restrict__ acc,
                   int P, int mol_shift) {
    __shared__ unsigned packed[16384];
    __shared__ unsigned binsu[4096];
    __shared__ float2 tabr[4][18];
    const int t = threadIdx.x;
    for (int i = t; i < 4096; i += NT) binsu[i] = 0u;
    if (t < 64) {
        int e = t & 15;
        tabr[t >> 4][e] = make_float2(-pre_tab[e], dfac_tab[e]);
    }
    {
        int4* dst = (int4*)packed;
        const int4* src = (const int4*)packed_ws;
        for (int i = t; i < 4096; i += NT) dst[i] = src[i];
    }
    __syncthreads();
    const float a2b   = (float)1.8897261258369282;
    const float rc    = (float)(5.2 * 1.8897261258369282);
    const float rcinv = (float)(1.0 / (5.2 * 1.8897261258369282));
    const int   copy  = t & 3;
    auto body = [&](unsigned ua0, unsigned ua1, float dang) {
        unsigned s0 = (packed[ua0 >> 4] >> ((ua0 & 15u) << 1)) & 3u;
        unsigned s1 = (packed[ua1 >> 4] >> ((ua1 & 15u) << 1)) & 3u;
        float2 td = tabr[copy][(s0 << 2) | s1];
        float db = dang * a2b;
        float x  = db * rcinv;
        float arg = td.y * db + (1.0f - 1.0f / (1.0f - x * x));
        float mag = td.x * __expf(arg);
        mag = (db < rc) ? mag : 0.0f;
        unsigned q = (unsigned)(mag * SCALE_F);
        atomicAdd(&binsu[ua0 >> mol_shift], q);
    };
    const int stride = (int)gridDim.x * NT;
    for (int p = (int)blockIdx.x * NT + t; p < P; p += stride)
        body((unsigned)ai[p], (unsigned)ai[P + p], dist[p]);
    __syncthreads();
    for (int i = t; i < 4096; i += NT) {
        unsigned v = binsu[i];
        if (v) atomicAdd(&acc[i], (unsigned long long)v);
    }
}

// ---------------------------------------------------------------------------
extern "C" void kernel_launch(void* const* d_in, const int* in_sizes, int n_in,
                              void* d_out, int out_size, void* d_ws, size_t ws_size,
                              hipStream_t stream) {
    const int*   species  = (const int*)d_in[0];
    const float* energies = (const float*)d_in[1];
    const int*   ai       = (const int*)d_in[2];
    const float* dist     = (const float*)d_in[3];
    const float* pre_tab  = (const float*)d_in[4];
    const float* dfac_tab = (const float*)d_in[5];

    const int n_species = in_sizes[0];            // 262144
    const int n_mol     = in_sizes[1];            // 4096
    const int P         = in_sizes[3];            // 16777216
    const int n_atoms   = n_species / n_mol;      // 64

    int mol_shift = 0;
    while ((1 << mol_shift) < n_atoms) ++mol_shift; // 6

    float* out   = (float*)d_out;
    float* out_e = out + n_species;

    const int    nwords    = n_species / 16;              // 16384
    const size_t packed_sz = (size_t)nwords * 4;          // 64KB
    const size_t acc_sz    = (size_t)n_mol * 8;           // 32KB

    unsigned*           packed = (unsigned*)d_ws;
    unsigned long long* acc    = (unsigned long long*)((char*)d_ws + packed_sz);
    (void)acc_sz;

    init_kernel<<<(n_species + 255) / 256, 256, 0, stream>>>(
        species, out, acc, n_species, n_mol);
    pack_species_kernel<<<(nwords + 255) / 256, 256, 0, stream>>>(
        species, packed, nwords);

    if ((P % (NBLK * CSTAGE)) == 0) {
        srb_async<<<NBLK, NT, 0, stream>>>(
            packed, ai, dist, pre_tab, dfac_tab, acc, P, mol_shift);
    } else {
        srb_fused_u32<<<NBLK, NT, 0, stream>>>(
            packed, ai, dist, pre_tab, dfac_tab, acc, P, mol_shift);
    }
    final_kernel<<<(n_mol + 255) / 256, 256, 0, stream>>>(
        acc, energies, out_e, n_mol);
}